// Round 1
// baseline (536.981 us; speedup 1.0000x reference)
//
#include <hip/hip_runtime.h>
#include <math.h>

#define NS 1024   // speakers
#define NU 64     // utterances per speaker
#define NE 256    // embedding dim
#define ROWS 16   // rows per block in main kernel

// ws layout (floats): Ct[NE][NS] transposed normalized speaker sums (262144),
// then normsum[NS] (1024).

__global__ __launch_bounds__(256) void centroid_kernel(
    const float* __restrict__ embeds, float* __restrict__ Ct,
    float* __restrict__ normsum) {
  int k = blockIdx.x;   // speaker
  int t = threadIdx.x;  // e index (NE == 256 == blockDim)
  const float* base = embeds + (size_t)k * NU * NE + t;
  float s = 0.f;
#pragma unroll
  for (int u = 0; u < NU; ++u) s += base[u * NE];
  // block-wide sum of squares -> ||sum_k||
  float sq = s * s;
#pragma unroll
  for (int off = 32; off; off >>= 1) sq += __shfl_xor(sq, off, 64);
  __shared__ float part[4];
  int wave = t >> 6, lane = t & 63;
  if (lane == 0) part[wave] = sq;
  __syncthreads();
  float n2 = part[0] + part[1] + part[2] + part[3];
  float nrm = sqrtf(n2);
  Ct[(size_t)t * NS + k] = s / nrm;  // transposed, normalized
  if (t == 0) normsum[k] = nrm;
}

__global__ __launch_bounds__(256) void main_kernel(
    const float* __restrict__ embeds, const float* __restrict__ Ct,
    const float* __restrict__ normsum, const float* __restrict__ wp,
    const float* __restrict__ bp, float* __restrict__ out) {
  __shared__ float rows[ROWS][NE];   // 16 KB
  __shared__ float nrm2[ROWS];
  __shared__ float redM[ROWS][4];
  __shared__ int   redI[ROWS][4];
  __shared__ float redS[ROWS][4];
  __shared__ float gtl[ROWS];

  int t = threadIdx.x;
  long long row0 = (long long)blockIdx.x * ROWS;

  // stage 16 rows (coalesced float4)
  {
    const float4* src = (const float4*)(embeds + row0 * NE);
    float4* dst = (float4*)&rows[0][0];
#pragma unroll
    for (int i = 0; i < (ROWS * NE / 4) / 256; ++i)
      dst[t + i * 256] = src[t + i * 256];
  }
  __syncthreads();

  // per-row ||e||^2 : 16 threads per row, shuffle-reduce within 16-lane group
  {
    int g = t >> 4, sub = t & 15;
    float p = 0.f;
#pragma unroll
    for (int i = 0; i < 16; ++i) {
      float v = rows[g][sub + 16 * i];
      p += v * v;
    }
#pragma unroll
    for (int off = 8; off; off >>= 1) p += __shfl_xor(p, off, 64);
    if (sub == 0) nrm2[g] = p;
  }
  __syncthreads();

  // main accumulation: thread owns k = 4t..4t+3 for all 16 rows
  float acc[ROWS][4];
#pragma unroll
  for (int r = 0; r < ROWS; ++r)
#pragma unroll
    for (int j = 0; j < 4; ++j) acc[r][j] = 0.f;

  const float4* ct4 = (const float4*)Ct;  // [NE][NS/4]
#pragma unroll 2
  for (int e = 0; e < NE; e += 2) {
    float4 c0 = ct4[(size_t)e * (NS / 4) + t];
    float4 c1 = ct4[(size_t)(e + 1) * (NS / 4) + t];
#pragma unroll
    for (int r = 0; r < ROWS; ++r) {
      float2 a = *(const float2*)&rows[r][e];
      acc[r][0] = fmaf(a.x, c0.x, acc[r][0]);
      acc[r][1] = fmaf(a.x, c0.y, acc[r][1]);
      acc[r][2] = fmaf(a.x, c0.z, acc[r][2]);
      acc[r][3] = fmaf(a.x, c0.w, acc[r][3]);
      acc[r][0] = fmaf(a.y, c1.x, acc[r][0]);
      acc[r][1] = fmaf(a.y, c1.y, acc[r][1]);
      acc[r][2] = fmaf(a.y, c1.z, acc[r][2]);
      acc[r][3] = fmaf(a.y, c1.w, acc[r][3]);
    }
  }

  float w = *wp, b = *bp;
  int k0 = t * 4;
  int wave = t >> 6, lane = t & 63;

  // logits (in place), diagonal fixup, per-row max+argmax reduce
#pragma unroll
  for (int r = 0; r < ROWS; ++r) {
    long long i = row0 + r;
    int jspk = (int)(i >> 6);
    float n = nrm2[r];
#pragma unroll
    for (int j = 0; j < 4; ++j) {
      float d = acc[r][j];
      float li = fmaf(w, d, b);
      if (k0 + j == jspk) {
        float ns = normsum[jspk];
        float Sv = d * ns;
        float denom2 = fmaf(ns, ns, n) - 2.f * Sv;  // ||sum - e||^2
        float val = (Sv - n) * rsqrtf(fmaxf(denom2, 1e-30f));
        li = fmaf(w, val, b);
        gtl[r] = li;
      }
      acc[r][j] = li;
    }
    float m = acc[r][0];
    int mi = k0;
#pragma unroll
    for (int j = 1; j < 4; ++j)
      if (acc[r][j] > m) { m = acc[r][j]; mi = k0 + j; }
#pragma unroll
    for (int off = 1; off < 64; off <<= 1) {
      float m2 = __shfl_xor(m, off, 64);
      int i2 = __shfl_xor(mi, off, 64);
      if (m2 > m || (m2 == m && i2 < mi)) { m = m2; mi = i2; }
    }
    if (lane == 0) { redM[r][wave] = m; redI[r][wave] = mi; }
  }
  __syncthreads();

  // per-row sum of exp(l - M)
#pragma unroll
  for (int r = 0; r < ROWS; ++r) {
    float M = redM[r][0];
#pragma unroll
    for (int q = 1; q < 4; ++q) M = fmaxf(M, redM[r][q]);
    float s = 0.f;
#pragma unroll
    for (int j = 0; j < 4; ++j) s += __expf(acc[r][j] - M);
#pragma unroll
    for (int off = 1; off < 64; off <<= 1) s += __shfl_xor(s, off, 64);
    if (lane == 0) redS[r][wave] = s;
  }
  __syncthreads();

  // final per-row combine on threads 0..15, then reduce and atomicAdd
  if (t < 16) {
    int r = t;
    long long i = row0 + r;
    int jspk = (int)(i >> 6);
    float M = redM[r][0];
    int MI = redI[r][0];
#pragma unroll
    for (int q = 1; q < 4; ++q) {
      float m2 = redM[r][q];
      int i2 = redI[r][q];
      if (m2 > M || (m2 == M && i2 < MI)) { M = m2; MI = i2; }
    }
    float ssum = redS[r][0] + redS[r][1] + redS[r][2] + redS[r][3];
    float lse = M + __logf(ssum);
    float lossr = lse - gtl[r];
    float corr = (MI == jspk) ? 1.f : 0.f;
#pragma unroll
    for (int off = 8; off; off >>= 1) {
      lossr += __shfl_xor(lossr, off, 64);
      corr += __shfl_xor(corr, off, 64);
    }
    if (t == 0) {
      atomicAdd(&out[0], lossr * (1.f / (float)(NS * NU)));
      atomicAdd(&out[1], corr * (1.f / (float)(NS * NU)));
    }
  }
}

extern "C" void kernel_launch(void* const* d_in, const int* in_sizes, int n_in,
                              void* d_out, int out_size, void* d_ws,
                              size_t ws_size, hipStream_t stream) {
  const float* embeds = (const float*)d_in[0];
  const float* w = (const float*)d_in[1];
  const float* b = (const float*)d_in[2];
  float* out = (float*)d_out;
  float* ws = (float*)d_ws;
  float* Ct = ws;                       // 256*1024 floats
  float* normsum = ws + NE * NS;        // 1024 floats

  hipMemsetAsync(d_out, 0, 2 * sizeof(float), stream);
  centroid_kernel<<<NS, 256, 0, stream>>>(embeds, Ct, normsum);
  main_kernel<<<(NS * NU) / ROWS, 256, 0, stream>>>(embeds, Ct, normsum, w, b,
                                                    out);
}

// Round 2
// 174.206 us; speedup vs baseline: 3.0824x; 3.0824x over previous
//
#include <hip/hip_runtime.h>
#include <math.h>

#define NS 1024   // speakers
#define NU 64     // utterances per speaker
#define NE 256    // embedding dim

typedef __attribute__((ext_vector_type(8))) short short8;
typedef __attribute__((ext_vector_type(4))) float f32x4;

// round-to-nearest-even fp32 -> bf16 bits
__device__ static inline unsigned short f2bf(float f) {
  unsigned int u = __float_as_uint(f);
  unsigned int r = (u + 0x7fffu + ((u >> 16) & 1u)) >> 16;
  return (unsigned short)r;
}

__device__ static inline void gld_lds16(const void* g, void* l) {
  __builtin_amdgcn_global_load_lds(
      (const __attribute__((address_space(1))) unsigned int*)g,
      (__attribute__((address_space(3))) unsigned int*)l, 16, 0, 0);
}

// ws layout: Cb (bf16, MFMA-B-fragment-permuted) 1024*256 ushorts, then
// normsum[1024] floats.
//
// Cb layout: global 1KB block G = (n>>4)*8 + (k>>5); within block,
// lane = ((k>>3)&3)*16 + (n&15), elem j = k&7:
//   idx(n,k) = G*512 + lane*8 + j      (ushort units)
// Chunk ch (64 cols) = blocks [ch*32, ch*32+32) -> contiguous 32 KB.

__global__ __launch_bounds__(256) void centroid_kernel(
    const float* __restrict__ embeds, unsigned short* __restrict__ Cb,
    float* __restrict__ normsum) {
  int k = blockIdx.x;   // speaker n
  int t = threadIdx.x;  // element index
  const float* base = embeds + (size_t)k * NU * NE + t;
  float s = 0.f;
#pragma unroll
  for (int u = 0; u < NU; ++u) s += base[u * NE];
  float sq = s * s;
#pragma unroll
  for (int off = 32; off; off >>= 1) sq += __shfl_xor(sq, off, 64);
  __shared__ float part[4];
  int wave = t >> 6, lane = t & 63;
  if (lane == 0) part[wave] = sq;
  __syncthreads();
  float n2 = part[0] + part[1] + part[2] + part[3];
  float nrm = sqrtf(n2);
  // permuted bf16 store
  int G = (k >> 4) * 8 + (t >> 5);
  int off = (((t >> 3) & 3) * 16 + (k & 15)) * 8 + (t & 7);
  Cb[(size_t)G * 512 + off] = f2bf(s / nrm);
  if (t == 0) normsum[k] = nrm;
}

__global__ __launch_bounds__(256, 2) void main_kernel(
    const float* __restrict__ embeds, const unsigned short* __restrict__ Cb,
    const float* __restrict__ normsum, const float* __restrict__ wp,
    const float* __restrict__ bp, float* __restrict__ out) {
  __shared__ __align__(16) unsigned short Bbuf[2][16384];  // 2 x 32 KB
  __shared__ float n2s[128];
  __shared__ float gtl[128];
  __shared__ float sE[128];
  __shared__ int aE[128];

  int t = threadIdx.x;
  int wave = t >> 6, lane = t & 63;
  int c = lane & 15, q = lane >> 4;
  int b0 = blockIdx.x;              // 0..511
  int jspk = b0 * 2 + (wave >> 1);  // this wave's speaker (diag column)
  int r0 = b0 * 128 + wave * 32;    // global row base for this wave

  float w = *wp, bia = *bp;
  float M0 = fabsf(w) + bia;  // >= any logit since cosines are in [-1,1]
  float ns = normsum[jspk];

  // ---- load A fragments (32 rows x 256 K per wave) into registers ----
  // A-frag layout: lane holds A[m = lane&15][k = q*8 + j], per (mtile, kstep)
  short8 af[2][8];
  float n2p[2];
#pragma unroll
  for (int mt = 0; mt < 2; ++mt) {
    const float* rowp = embeds + (size_t)(r0 + mt * 16 + c) * NE;
    float acc2 = 0.f;
#pragma unroll
    for (int s = 0; s < 8; ++s) {
      int k0 = s * 32 + q * 8;
      float4 x = *(const float4*)(rowp + k0);
      float4 y = *(const float4*)(rowp + k0 + 4);
      acc2 += x.x * x.x + x.y * x.y + x.z * x.z + x.w * x.w;
      acc2 += y.x * y.x + y.y * y.y + y.z * y.z + y.w * y.w;
      short8 f;
      f[0] = (short)f2bf(x.x); f[1] = (short)f2bf(x.y);
      f[2] = (short)f2bf(x.z); f[3] = (short)f2bf(x.w);
      f[4] = (short)f2bf(y.x); f[5] = (short)f2bf(y.y);
      f[6] = (short)f2bf(y.z); f[7] = (short)f2bf(y.w);
      af[mt][s] = f;
    }
    n2p[mt] = acc2;
  }
  // row norm^2: sum over the 4 q-groups (each covers 64 of 256 elements)
#pragma unroll
  for (int mt = 0; mt < 2; ++mt) {
    n2p[mt] += __shfl_xor(n2p[mt], 16, 64);
    n2p[mt] += __shfl_xor(n2p[mt], 32, 64);
  }
  if (q == 0) {
    n2s[wave * 32 + c] = n2p[0];
    n2s[wave * 32 + 16 + c] = n2p[1];
  }

  // ---- softmax running state (per lane: 2 mtiles x 4 regs = 8 row-slots) ----
  float ssum[2][4];
  float mx[2][4];
  int ai[2][4];
#pragma unroll
  for (int mt = 0; mt < 2; ++mt)
#pragma unroll
    for (int r = 0; r < 4; ++r) {
      ssum[mt][r] = 0.f;
      mx[mt][r] = -1e30f;
      ai[mt][r] = 0;
    }

  // ---- stage chunk 0 ----
  {
    const unsigned short* src = Cb;  // chunk 0
#pragma unroll
    for (int i = 0; i < 8; ++i) {
      int blk = i * 4 + wave;
      gld_lds16(src + blk * 512 + lane * 8, &Bbuf[0][blk * 512 + lane * 8]);
    }
  }
  __syncthreads();  // drains vmcnt; also publishes n2s

  // ---- main loop over 16 N-chunks of 64 columns ----
  for (int ch = 0; ch < 16; ++ch) {
    const unsigned short* buf = Bbuf[ch & 1];
    if (ch + 1 < 16) {
      const unsigned short* src = Cb + (size_t)(ch + 1) * 16384;
      unsigned short* dst = Bbuf[(ch + 1) & 1];
#pragma unroll
      for (int i = 0; i < 8; ++i) {
        int blk = i * 4 + wave;
        gld_lds16(src + blk * 512 + lane * 8, dst + blk * 512 + lane * 8);
      }
    }

    for (int nt = 0; nt < 4; ++nt) {
      f32x4 acc0 = {0.f, 0.f, 0.f, 0.f};
      f32x4 acc1 = {0.f, 0.f, 0.f, 0.f};
#pragma unroll
      for (int s = 0; s < 8; ++s) {
        short8 bfrag = *(const short8*)(buf + ((nt * 8 + s) * 64 + lane) * 8);
        acc0 = __builtin_amdgcn_mfma_f32_16x16x32_bf16(af[0][s], bfrag, acc0,
                                                       0, 0, 0);
        acc1 = __builtin_amdgcn_mfma_f32_16x16x32_bf16(af[1][s], bfrag, acc1,
                                                       0, 0, 0);
      }
      int col = ch * 64 + nt * 16 + c;
      bool isdiag = (col == jspk);
#pragma unroll
      for (int mt = 0; mt < 2; ++mt) {
        f32x4 a = mt ? acc1 : acc0;
#pragma unroll
        for (int r = 0; r < 4; ++r) {
          float d = a[r];
          float l = fmaf(w, d, bia);
          if (isdiag) {
            int rl = wave * 32 + mt * 16 + q * 4 + r;
            float n2 = n2s[rl];
            float Sv = d * ns;
            float den = fmaxf(fmaf(ns, ns, n2) - 2.f * Sv, 1e-30f);
            l = fmaf(w, (Sv - n2) * __frsqrt_rn(den), bia);
            gtl[rl] = l;
          }
          ssum[mt][r] += __expf(l - M0);
          if (l > mx[mt][r]) {
            mx[mt][r] = l;
            ai[mt][r] = col;
          }
        }
      }
    }
    __syncthreads();
  }

  // ---- cross-lane (over the 16 column-lanes) reduction per row-slot ----
#pragma unroll
  for (int mt = 0; mt < 2; ++mt)
#pragma unroll
    for (int r = 0; r < 4; ++r) {
      float s = ssum[mt][r];
      s += __shfl_xor(s, 1, 64);
      s += __shfl_xor(s, 2, 64);
      s += __shfl_xor(s, 4, 64);
      s += __shfl_xor(s, 8, 64);
      float m = mx[mt][r];
      int idx = ai[mt][r];
#pragma unroll
      for (int off = 1; off < 16; off <<= 1) {
        float m2 = __shfl_xor(m, off, 64);
        int i2 = __shfl_xor(idx, off, 64);
        if (m2 > m || (m2 == m && i2 < idx)) { m = m2; idx = i2; }
      }
      if (c == 0) {
        int rl = wave * 32 + mt * 16 + q * 4 + r;
        sE[rl] = s;
        aE[rl] = idx;
      }
    }
  __syncthreads();

  // ---- final per-row combine (128 rows on waves 0,1) ----
  if (t < 128) {
    int spk = b0 * 2 + (t >> 6);
    float lse = M0 + __logf(sE[t]);
    float lossr = lse - gtl[t];
    float corr = (aE[t] == spk) ? 1.f : 0.f;
#pragma unroll
    for (int off = 32; off; off >>= 1) {
      lossr += __shfl_xor(lossr, off, 64);
      corr += __shfl_xor(corr, off, 64);
    }
    if ((t & 63) == 0) {
      const float inv = 1.f / (float)(NS * NU);
      atomicAdd(&out[0], lossr * inv);
      atomicAdd(&out[1], corr * inv);
    }
  }
}

extern "C" void kernel_launch(void* const* d_in, const int* in_sizes, int n_in,
                              void* d_out, int out_size, void* d_ws,
                              size_t ws_size, hipStream_t stream) {
  const float* embeds = (const float*)d_in[0];
  const float* w = (const float*)d_in[1];
  const float* b = (const float*)d_in[2];
  float* out = (float*)d_out;
  unsigned short* Cb = (unsigned short*)d_ws;          // 1024*256 bf16
  float* normsum = (float*)(Cb + NS * NE);             // 1024 floats

  hipMemsetAsync(d_out, 0, 2 * sizeof(float), stream);
  centroid_kernel<<<NS, 256, 0, stream>>>(embeds, Cb, normsum);
  main_kernel<<<NS * NU / 128, 256, 0, stream>>>(embeds, Cb, normsum, w, b,
                                                 out);
}